// Round 13
// baseline (78.262 us; speedup 1.0000x reference)
//
#include <hip/hip_runtime.h>
#include <hip/hip_cooperative_groups.h>
#include <math.h>

#define NPTS 1000
#define NGRID 256
#define NEWTON_ITERS 2
#define PI_D 3.14159265358979323846

// Y grid: linspace(1e-3, 0.999, 1000). YD grid: linspace(1e-3, 1.0, 1000).
#define HY   ((0.999 - 1e-3) / 999.0)
#define Y0C  (1e-3)
#define HD   ((1.0 - 1e-3) / 999.0)

// trapz+extrapolation weights (closed form — uniform grid)
#define WY0   (0.5 * HY + Y0C + 0.5 * Y0C * Y0C / HY)
#define WY1   (HY - 0.5 * Y0C * Y0C / HY)
#define WY999 (0.5 * HY + 0.5 * (1.0 - 0.999))
#define WD0   (0.5 * (Y0C + HD))
#define WD999 (0.5 * HD)

struct SCf {
    float c[11], pc[11], bc[6], dbc[5], S, sa;
};

__device__ inline void make_scf(const float* a, const float* b, SCf& s) {
    float af[6], bf[6];
    af[0] = 1.0f; bf[0] = 1.0f;
    #pragma unroll
    for (int i = 0; i < 5; ++i) { af[i+1] = a[i]; bf[i+1] = b[i]; }
    #pragma unroll
    for (int k = 0; k < 11; ++k) s.c[k] = 0.0f;
    #pragma unroll
    for (int i = 0; i < 6; ++i)
        #pragma unroll
        for (int j = 0; j < 6; ++j)
            s.c[i+j] = fmaf(4.0f * af[i], af[j], s.c[i+j]);
    const float INVK[11] = { -0.25f, -1.0f/3.0f, -0.5f, -1.0f, 0.0f,
                              1.0f, 0.5f, 1.0f/3.0f, 0.25f, 0.2f, 1.0f/6.0f };
    float S = 0.0f;
    #pragma unroll
    for (int k = 0; k < 11; ++k) { s.pc[k] = s.c[k] * INVK[k]; S += s.pc[k]; }
    s.S = S;
    float sa = 0.0f;
    #pragma unroll
    for (int i = 0; i < 5; ++i) sa = fmaf(a[i], a[i], sa);
    s.sa = sa;
    #pragma unroll
    for (int i = 0; i < 6; ++i) s.bc[i] = bf[i];
    #pragma unroll
    for (int i = 1; i < 6; ++i) s.dbc[i-1] = (float)i * bf[i];
}

__device__ inline float eval_f_f(float z, float lnz, float z4, const SCf& s) {
    float P = s.pc[10];
    #pragma unroll
    for (int k = 9; k >= 0; --k) P = fmaf(P, z, s.pc[k]);
    return s.S * z4 - P - s.c[4] * z4 * lnz + 0.004f * s.sa * z4 * (1.0f - z);
}
__device__ inline float eval_Q_f(float z, const SCf& s) {
    float Q = s.c[10];
    #pragma unroll
    for (int k = 9; k >= 0; --k) Q = fmaf(Q, z, s.c[k]);
    return Q;
}
__device__ inline float eval_bv_f(float z, const SCf& s) {
    float B = s.bc[5];
    #pragma unroll
    for (int k = 4; k >= 0; --k) B = fmaf(B, z, s.bc[k]);
    return B;
}
__device__ inline float eval_dbv_f(float z, const SCf& s) {
    float D = s.dbc[4];
    #pragma unroll
    for (int k = 3; k >= 0; --k) D = fmaf(D, z, s.dbc[k]);
    return D;
}

struct PtCf { float y, u, lnu, wt, inv_u; };
struct ItSf { float zs, lnzs, zs4, fs, inv_fs, inv_zs, sdf; };

__device__ inline void make_points(int tid, PtCf* p) {
    #pragma unroll
    for (int j = 0; j < 2; ++j) {
        int k = tid + j * 512;
        int kk = (k < NPTS) ? k : (NPTS - 1);
        float y = (float)(Y0C + (double)kk * HY);
        float u = (1.0f - y) * (1.0f + y);
        p[j].y = y;
        p[j].u = u;
        p[j].lnu = __logf(u);
        p[j].inv_u = __fdividef(1.0f, u);
        float wt;
        if (k >= NPTS)      wt = 0.0f;
        else if (k == 0)    wt = (float)WY0;
        else if (k == 1)    wt = (float)WY1;
        else if (k == 999)  wt = (float)WY999;
        else                wt = (float)HY;
        p[j].wt = wt;
    }
}

__device__ inline void iter_scalars_f(float zs, const SCf& s, ItSf& it) {
    it.zs = zs;
    it.lnzs = __logf(zs);
    float z2 = zs * zs;
    it.zs4 = z2 * z2;
    it.inv_zs = __fdividef(1.0f, zs);
    float f = eval_f_f(zs, it.lnzs, it.zs4, s);
    float Q = eval_Q_f(zs, s);
    float dfs = (4.0f * f - Q) * it.inv_zs - 0.004f * s.sa * it.zs4;
    it.fs = f;
    it.inv_fs = __fdividef(1.0f, f);
    it.sdf = zs * dfs * it.inv_fs;   // zs*dfs/fs
}

template <bool NL, bool ND>
__device__ inline void integrands_f(const PtCf& p, const ItSf& is, const SCf& s,
                                    float& IL, float& ID) {
    float u = p.u;
    float w2 = u * u, w4 = w2 * w2;
    float z   = is.zs * u;
    float lnz = is.lnzs + p.lnu;
    float z4  = is.zs4 * w4;
    float f = eval_f_f(z, lnz, z4, s);
    float bv = eval_bv_f(z, s);
    float inv_f = __fdividef(1.0f, f);
    float sqrtg = fabsf(bv) * rsqrtf(f);
    float fofs = f * is.inv_fs;
    float iu2 = p.inv_u * p.inv_u;
    float r4 = iu2 * iu2;                // zs^4/z^4
    float A = fofs * r4;
    float r = rsqrtf(A - 1.0f);
    if (NL) {
        IL = sqrtg * p.y * r;
    }
    if (ND) {
        float Q = eval_Q_f(z, s);
        float inv_z = is.inv_zs * p.inv_u;
        float df = (4.0f * f - Q) * inv_z - 0.004f * s.sa * z4;
        float dbv = eval_dbv_f(z, s);
        float t = z * (2.0f * __fdividef(dbv, bv) - df * inv_f);   // z*dg/g
        float i1 = A * (is.sdf + 2.0f + t) - r4 * z * df * is.inv_fs - 2.0f - t;
        ID = i1 * 2.0f * p.y * sqrtg * (r * r * r);
    }
}

__device__ inline void block_reduce2(double& sx, double& sy, double2* lds, int tid) {
    #pragma unroll
    for (int off = 32; off > 0; off >>= 1) {
        sx += __shfl_xor(sx, off);
        sy += __shfl_xor(sy, off);
    }
    int wid = tid >> 6;
    if ((tid & 63) == 0) lds[wid] = make_double2(sx, sy);
    __syncthreads();
    double rx = 0.0, ry = 0.0;
    #pragma unroll
    for (int w = 0; w < 8; ++w) { rx += lds[w].x; ry += lds[w].y; }
    __syncthreads();
    sx = rx; sy = ry;
}

__device__ inline double grid_zs(int i) {
    return 0.05 + (double)i * (0.999 - 0.05) / 255.0;
}

// ---- phase-1 body: masked Lg entry for grid index blk ----
__device__ inline void do_grid_entry(int blk, int tid, const SCf& sc, const PtCf* p,
                                     double2* red, float* W) {
    float zs = (float)grid_zs(blk);
    ItSf is;
    iter_scalars_f(zs, sc, is);
    float sLf = 0.0f, sDf = 0.0f;
    #pragma unroll
    for (int j = 0; j < 2; ++j) {
        float IL, ID;
        integrands_f<true, true>(p[j], is, sc, IL, ID);
        sLf = fmaf(p[j].wt, IL, sLf);
        sDf = fmaf(p[j].wt, ID, sDf);
    }
    double sL = (double)sLf, sD = (double)sDf;
    block_reduce2(sL, sD, red, tid);
    if (tid == 0) {
        W[blk] = (sD > 0.0) ? (float)(4.0 * (double)zs * sL / PI_D) : 1e30f;
    }
}

// ---- phase-2 body: argmin init + Newton + Vc/Vd for L index blk ----
__device__ inline void do_newton(int blk, int tid, const SCf& sc, const PtCf* p,
                                 double2* red, float* wv, int* wi,
                                 const float* Ls, const float* logcoef, const float* W,
                                 float* out, int out_size, int B) {
    float Ltf = Ls[blk];
    double Lt = (double)Ltf;

    // argmin |Lg - L| over 256 masked entries (first-min tie-break)
    float v = (tid < NGRID) ? fabsf(W[tid] - Ltf) : 3e38f;
    int idx = (tid < NGRID) ? tid : (1 << 30);
    #pragma unroll
    for (int off = 32; off > 0; off >>= 1) {
        float ov = __shfl_xor(v, off);
        int oi = __shfl_xor(idx, off);
        if (ov < v || (ov == v && oi < idx)) { v = ov; idx = oi; }
    }
    if ((tid & 63) == 0) { wv[tid >> 6] = v; wi[tid >> 6] = idx; }
    __syncthreads();
    v = wv[0]; idx = wi[0];
    #pragma unroll
    for (int w = 1; w < 8; ++w) {
        if (wv[w] < v || (wv[w] == v && wi[w] < idx)) { v = wv[w]; idx = wi[w]; }
    }
    double zs = grid_zs(idx);

    // Newton (combined L + dL pass; f32 integrands, f64 update)
    for (int itn = 0; itn < NEWTON_ITERS; ++itn) {
        ItSf is;
        iter_scalars_f((float)zs, sc, is);
        float sLf = 0.0f, sDf = 0.0f;
        #pragma unroll
        for (int j = 0; j < 2; ++j) {
            float IL, ID;
            integrands_f<true, true>(p[j], is, sc, IL, ID);
            sLf = fmaf(p[j].wt, IL, sLf);
            sDf = fmaf(p[j].wt, ID, sDf);
        }
        double sL = (double)sLf, sD = (double)sDf;
        block_reduce2(sL, sD, red, tid);
        double L_  = 4.0 * zs * sL / PI_D;
        double dL  = sD / PI_D;
        zs = zs - (L_ - Lt) / dL;
        zs = fmin(fmax(zs, 1e-3), 0.999);
    }

    // Vc (Y grid) + Vd (YD grid), fused; sqrt(f*g)=|bv| exactly.
    ItSf is;
    iter_scalars_f((float)zs, sc, is);
    float omzs = (float)(1.0 - zs);
    float sVcf = 0.0f, sVdf = 0.0f;
    #pragma unroll
    for (int j = 0; j < 2; ++j) {
        int k = tid + j * 512;
        int kk = (k < NPTS) ? k : (NPTS - 1);
        {   // connected
            float u = p[j].u;
            float w2 = u * u, w4 = w2 * w2;
            float z   = is.zs * u;
            float lnz = is.lnzs + p[j].lnu;
            float z4  = is.zs4 * w4;
            float f = eval_f_f(z, lnz, z4, sc);
            float bv = eval_bv_f(z, sc);
            float inv_f = __fdividef(1.0f, f);
            float iu2 = p[j].inv_u * p[j].inv_u;
            float arg = fmaf(-w4 * is.fs, inv_f, 1.0f);   // 1 - w4*fs/f
            float Ic = fabsf(bv) * (rsqrtf(arg) - 1.0f) * p[j].y * iu2;
            sVcf = fmaf(p[j].wt, Ic, sVcf);
        }
        {   // disconnected: integrand = |bv(z)|/z^2
            float yd = (float)(Y0C + (double)kk * HD);
            float wyd;
            if (k >= NPTS)      wyd = 0.0f;
            else if (k == 0)    wyd = (float)WD0;
            else if (k == 999)  wyd = (float)WD999;
            else                wyd = (float)HD;
            float z = fmaf(-omzs, yd, 1.0f);
            float bv = eval_bv_f(z, sc);
            float Id = fabsf(bv) * __fdividef(1.0f, z * z);
            sVdf = fmaf(wyd, Id, sVdf);
        }
    }
    double sVc = (double)sVcf, sVd = (double)sVdf;
    block_reduce2(sVc, sVd, red, tid);
    double elc = exp((double)logcoef[0]);
    double Vc = elc * PI_D * 4.0 * sVc / zs;
    double Vd = elc * PI_D * 2.0 * (1.0 - zs) * (0.5 * Y0C + sVd);
    double outv = Vc - Vd;

    if (tid == 0) {
        if (out_size >= 2 * B) {
            out[2 * blk]     = (float)outv;
            out[2 * blk + 1] = 0.0f;
        } else {
            out[blk] = (float)outv;
        }
    }
}

// ---------------- Fused cooperative kernel ----------------
__global__ __launch_bounds__(512, 4) void k_fused(const float* Ls, const float* a,
                                                  const float* b, const float* logcoef,
                                                  float* W, float* out, int out_size, int B) {
    namespace cg = cooperative_groups;
    __shared__ double2 red[8];
    __shared__ float wv[8];
    __shared__ int wi[8];
    int tid = threadIdx.x, blk = blockIdx.x;
    SCf sc;
    make_scf(a, b, sc);
    PtCf p[2];
    make_points(tid, p);

    if (blk < NGRID) do_grid_entry(blk, tid, sc, p, red, W);

    cg::this_grid().sync();

    if (blk < B)
        do_newton(blk, tid, sc, p, red, wv, wi, Ls, logcoef, W, out, out_size, B);
}

// ---------------- Fallback 2-kernel path ----------------
__global__ __launch_bounds__(512, 4) void k_grid(const float* a, const float* b, float* W) {
    __shared__ double2 red[8];
    int tid = threadIdx.x, blk = blockIdx.x;
    SCf sc;
    make_scf(a, b, sc);
    PtCf p[2];
    make_points(tid, p);
    do_grid_entry(blk, tid, sc, p, red, W);
}

__global__ __launch_bounds__(512, 4) void k_newton(const float* Ls, const float* a,
                                                   const float* b, const float* logcoef,
                                                   const float* W, float* out,
                                                   int out_size, int B) {
    __shared__ double2 red[8];
    __shared__ float wv[8];
    __shared__ int wi[8];
    int tid = threadIdx.x, blk = blockIdx.x;
    SCf sc;
    make_scf(a, b, sc);
    PtCf p[2];
    make_points(tid, p);
    do_newton(blk, tid, sc, p, red, wv, wi, Ls, logcoef, W, out, out_size, B);
}

extern "C" void kernel_launch(void* const* d_in, const int* in_sizes, int n_in,
                              void* d_out, int out_size, void* d_ws, size_t ws_size,
                              hipStream_t stream) {
    const float* Ls = (const float*)d_in[0];
    const float* a  = (const float*)d_in[1];
    const float* b  = (const float*)d_in[2];
    const float* lc = (const float*)d_in[3];
    float* W = (float*)d_ws;
    float* outp = (float*)d_out;
    int B = in_sizes[0];
    int os = out_size;

    int grid = (B > NGRID) ? B : NGRID;
    void* args[] = { (void*)&Ls, (void*)&a, (void*)&b, (void*)&lc,
                     (void*)&W, (void*)&outp, (void*)&os, (void*)&B };
    hipError_t err = hipLaunchCooperativeKernel((void*)k_fused, dim3(grid), dim3(512),
                                                args, 0, stream);
    if (err != hipSuccess) {
        // fallback: two plain launches (same math)
        hipLaunchKernelGGL(k_grid, dim3(NGRID), dim3(512), 0, stream, a, b, W);
        hipLaunchKernelGGL(k_newton, dim3(B), dim3(512), 0, stream,
                           Ls, a, b, lc, W, outp, os, B);
    }
}

// Round 14
// 20.807 us; speedup vs baseline: 3.7613x; 3.7613x over previous
//
#include <hip/hip_runtime.h>
#include <math.h>

#define NPTS 1000
#define NGRID 256
#define NEWTON_ITERS 2
#define PI_D 3.14159265358979323846

// Y grid: linspace(1e-3, 0.999, 1000). YD grid: linspace(1e-3, 1.0, 1000).
#define HY   ((0.999 - 1e-3) / 999.0)
#define Y0C  (1e-3)
#define HD   ((1.0 - 1e-3) / 999.0)

// trapz+extrapolation weights (closed form — uniform grid)
#define WY0   (0.5 * HY + Y0C + 0.5 * Y0C * Y0C / HY)
#define WY1   (HY - 0.5 * Y0C * Y0C / HY)
#define WY999 (0.5 * HY + 0.5 * (1.0 - 0.999))
#define WD0   (0.5 * (Y0C + HD))
#define WD999 (0.5 * HD)

struct SCf {
    float c[11], pc[11], bc[6], dbc[5], S, sa;
};

// Per-thread f32 coefficient folding (~70 FLOPs, all-register).
__device__ inline void make_scf(const float* a, const float* b, SCf& s) {
    float af[6], bf[6];
    af[0] = 1.0f; bf[0] = 1.0f;
    #pragma unroll
    for (int i = 0; i < 5; ++i) { af[i+1] = a[i]; bf[i+1] = b[i]; }
    #pragma unroll
    for (int k = 0; k < 11; ++k) s.c[k] = 0.0f;
    #pragma unroll
    for (int i = 0; i < 6; ++i)
        #pragma unroll
        for (int j = 0; j < 6; ++j)
            s.c[i+j] = fmaf(4.0f * af[i], af[j], s.c[i+j]);
    const float INVK[11] = { -0.25f, -1.0f/3.0f, -0.5f, -1.0f, 0.0f,
                              1.0f, 0.5f, 1.0f/3.0f, 0.25f, 0.2f, 1.0f/6.0f };
    float S = 0.0f;
    #pragma unroll
    for (int k = 0; k < 11; ++k) { s.pc[k] = s.c[k] * INVK[k]; S += s.pc[k]; }
    s.S = S;
    float sa = 0.0f;
    #pragma unroll
    for (int i = 0; i < 5; ++i) sa = fmaf(a[i], a[i], sa);
    s.sa = sa;
    #pragma unroll
    for (int i = 0; i < 6; ++i) s.bc[i] = bf[i];
    #pragma unroll
    for (int i = 1; i < 6; ++i) s.dbc[i-1] = (float)i * bf[i];
}

__device__ inline float eval_f_f(float z, float lnz, float z4, const SCf& s) {
    float P = s.pc[10];
    #pragma unroll
    for (int k = 9; k >= 0; --k) P = fmaf(P, z, s.pc[k]);
    return s.S * z4 - P - s.c[4] * z4 * lnz + 0.004f * s.sa * z4 * (1.0f - z);
}
__device__ inline float eval_Q_f(float z, const SCf& s) {
    float Q = s.c[10];
    #pragma unroll
    for (int k = 9; k >= 0; --k) Q = fmaf(Q, z, s.c[k]);
    return Q;
}
__device__ inline float eval_bv_f(float z, const SCf& s) {
    float B = s.bc[5];
    #pragma unroll
    for (int k = 4; k >= 0; --k) B = fmaf(B, z, s.bc[k]);
    return B;
}
__device__ inline float eval_dbv_f(float z, const SCf& s) {
    float D = s.dbc[4];
    #pragma unroll
    for (int k = 3; k >= 0; --k) D = fmaf(D, z, s.dbc[k]);
    return D;
}

struct PtCf { float y, u, lnu, wt, inv_u; };
struct ItSf { float zs, lnzs, zs4, fs, inv_fs, inv_zs, sdf; };

// Per-thread point constants (f32 hot ops; y from f64 fma for grid fidelity).
__device__ inline void make_points(int tid, PtCf* p) {
    #pragma unroll
    for (int j = 0; j < 2; ++j) {
        int k = tid + j * 512;
        int kk = (k < NPTS) ? k : (NPTS - 1);
        float y = (float)(Y0C + (double)kk * HY);
        float u = (1.0f - y) * (1.0f + y);
        p[j].y = y;
        p[j].u = u;
        p[j].lnu = __logf(u);
        p[j].inv_u = __fdividef(1.0f, u);
        float wt;
        if (k >= NPTS)      wt = 0.0f;
        else if (k == 0)    wt = (float)WY0;
        else if (k == 1)    wt = (float)WY1;
        else if (k == 999)  wt = (float)WY999;
        else                wt = (float)HY;
        p[j].wt = wt;
    }
}

__device__ inline void iter_scalars_f(float zs, const SCf& s, ItSf& it) {
    it.zs = zs;
    it.lnzs = __logf(zs);
    float z2 = zs * zs;
    it.zs4 = z2 * z2;
    it.inv_zs = __fdividef(1.0f, zs);
    float f = eval_f_f(zs, it.lnzs, it.zs4, s);
    float Q = eval_Q_f(zs, s);
    float dfs = (4.0f * f - Q) * it.inv_zs - 0.004f * s.sa * it.zs4;
    it.fs = f;
    it.inv_fs = __fdividef(1.0f, f);
    it.sdf = zs * dfs * it.inv_fs;   // zs*dfs/fs
}

// Combined L / dL integrands (f32). sqrt(1-z/zs)=y; 1/(Am1^1.5)=rsqrt^3.
template <bool NL, bool ND>
__device__ inline void integrands_f(const PtCf& p, const ItSf& is, const SCf& s,
                                    float& IL, float& ID) {
    float u = p.u;
    float w2 = u * u, w4 = w2 * w2;
    float z   = is.zs * u;
    float lnz = is.lnzs + p.lnu;
    float z4  = is.zs4 * w4;
    float f = eval_f_f(z, lnz, z4, s);
    float bv = eval_bv_f(z, s);
    float inv_f = __fdividef(1.0f, f);
    float sqrtg = fabsf(bv) * rsqrtf(f);
    float fofs = f * is.inv_fs;
    float iu2 = p.inv_u * p.inv_u;
    float r4 = iu2 * iu2;                // zs^4/z^4
    float A = fofs * r4;
    float r = rsqrtf(A - 1.0f);
    if (NL) {
        IL = sqrtg * p.y * r;
    }
    if (ND) {
        float Q = eval_Q_f(z, s);
        float inv_z = is.inv_zs * p.inv_u;
        float df = (4.0f * f - Q) * inv_z - 0.004f * s.sa * z4;
        float dbv = eval_dbv_f(z, s);
        float t = z * (2.0f * __fdividef(dbv, bv) - df * inv_f);   // z*dg/g
        float i1 = A * (is.sdf + 2.0f + t) - r4 * z * df * is.inv_fs - 2.0f - t;
        ID = i1 * 2.0f * p.y * sqrtg * (r * r * r);
    }
}

// deterministic block reduction of 2 doubles (512 threads = 8 waves)
__device__ inline void block_reduce2(double& sx, double& sy, double2* lds, int tid) {
    #pragma unroll
    for (int off = 32; off > 0; off >>= 1) {
        sx += __shfl_xor(sx, off);
        sy += __shfl_xor(sy, off);
    }
    int wid = tid >> 6;
    if ((tid & 63) == 0) lds[wid] = make_double2(sx, sy);
    __syncthreads();
    double rx = 0.0, ry = 0.0;
    #pragma unroll
    for (int w = 0; w < 8; ++w) { rx += lds[w].x; ry += lds[w].y; }
    __syncthreads();
    sx = rx; sy = ry;
}

__device__ inline double grid_zs(int i) {
    return 0.05 + (double)i * (0.999 - 0.05) / 255.0;
}

// ---- Kernel 1: Lg (masked to rising branch) over a FIXED zs grid ----
__global__ __launch_bounds__(512, 4) void k_grid(const float* a, const float* b, float* W) {
    __shared__ double2 red[8];
    int tid = threadIdx.x, blk = blockIdx.x;
    SCf sc;
    make_scf(a, b, sc);
    PtCf p[2];
    make_points(tid, p);

    float zs = (float)grid_zs(blk);
    ItSf is;
    iter_scalars_f(zs, sc, is);
    float sLf = 0.0f, sDf = 0.0f;
    #pragma unroll
    for (int j = 0; j < 2; ++j) {
        float IL, ID;
        integrands_f<true, true>(p[j], is, sc, IL, ID);
        sLf = fmaf(p[j].wt, IL, sLf);
        sDf = fmaf(p[j].wt, ID, sDf);
    }
    double sL = (double)sLf, sD = (double)sDf;
    block_reduce2(sL, sD, red, tid);
    if (tid == 0) {
        // mask non-rising-branch candidates (dL <= 0)
        W[blk] = (sD > 0.0) ? (float)(4.0 * (double)zs * sL / PI_D) : 1e30f;
    }
}

// ---- Kernel 2: argmin init + Newton + Vc/Vd ----
__global__ __launch_bounds__(512, 4) void k_newton(const float* Ls, const float* a,
                                                   const float* b, const float* logcoef,
                                                   const float* W, float* out,
                                                   int out_size, int B) {
    __shared__ double2 red[8];
    __shared__ float wv[8];
    __shared__ int wi[8];
    int tid = threadIdx.x, blk = blockIdx.x;
    SCf sc;
    make_scf(a, b, sc);

    float Ltf = Ls[blk];
    double Lt = (double)Ltf;

    // argmin |Lg - L| over 256 masked entries (first-min tie-break)
    float v = (tid < NGRID) ? fabsf(W[tid] - Ltf) : 3e38f;
    int idx = (tid < NGRID) ? tid : (1 << 30);
    #pragma unroll
    for (int off = 32; off > 0; off >>= 1) {
        float ov = __shfl_xor(v, off);
        int oi = __shfl_xor(idx, off);
        if (ov < v || (ov == v && oi < idx)) { v = ov; idx = oi; }
    }
    if ((tid & 63) == 0) { wv[tid >> 6] = v; wi[tid >> 6] = idx; }
    __syncthreads();
    v = wv[0]; idx = wi[0];
    #pragma unroll
    for (int w = 1; w < 8; ++w) {
        if (wv[w] < v || (wv[w] == v && wi[w] < idx)) { v = wv[w]; idx = wi[w]; }
    }
    double zs = grid_zs(idx);

    PtCf p[2];
    make_points(tid, p);

    // Newton (combined L + dL pass; f32 integrands, f64 update)
    for (int itn = 0; itn < NEWTON_ITERS; ++itn) {
        ItSf is;
        iter_scalars_f((float)zs, sc, is);
        float sLf = 0.0f, sDf = 0.0f;
        #pragma unroll
        for (int j = 0; j < 2; ++j) {
            float IL, ID;
            integrands_f<true, true>(p[j], is, sc, IL, ID);
            sLf = fmaf(p[j].wt, IL, sLf);
            sDf = fmaf(p[j].wt, ID, sDf);
        }
        double sL = (double)sLf, sD = (double)sDf;
        block_reduce2(sL, sD, red, tid);
        double L_  = 4.0 * zs * sL / PI_D;
        double dL  = sD / PI_D;
        zs = zs - (L_ - Lt) / dL;
        zs = fmin(fmax(zs, 1e-3), 0.999);   // domain clamp (no-op at convergence)
    }

    // Vc (Y grid) + Vd (YD grid), fused; sqrt(f*g)=|bv| exactly.
    ItSf is;
    iter_scalars_f((float)zs, sc, is);
    float omzs = (float)(1.0 - zs);
    float sVcf = 0.0f, sVdf = 0.0f;
    #pragma unroll
    for (int j = 0; j < 2; ++j) {
        int k = tid + j * 512;
        int kk = (k < NPTS) ? k : (NPTS - 1);
        {   // connected: z = zs*(1-y)(1+y)
            float u = p[j].u;
            float w2 = u * u, w4 = w2 * w2;
            float z   = is.zs * u;
            float lnz = is.lnzs + p[j].lnu;
            float z4  = is.zs4 * w4;
            float f = eval_f_f(z, lnz, z4, sc);
            float bv = eval_bv_f(z, sc);
            float inv_f = __fdividef(1.0f, f);
            float iu2 = p[j].inv_u * p[j].inv_u;
            float arg = fmaf(-w4 * is.fs, inv_f, 1.0f);   // 1 - w4*fs/f
            float Ic = fabsf(bv) * (rsqrtf(arg) - 1.0f) * p[j].y * iu2;
            sVcf = fmaf(p[j].wt, Ic, sVcf);
        }
        {   // disconnected: z = 1-(1-zs)*yd ; integrand = |bv(z)|/z^2
            float yd = (float)(Y0C + (double)kk * HD);
            float wyd;
            if (k >= NPTS)      wyd = 0.0f;
            else if (k == 0)    wyd = (float)WD0;
            else if (k == 999)  wyd = (float)WD999;
            else                wyd = (float)HD;
            float z = fmaf(-omzs, yd, 1.0f);
            float bv = eval_bv_f(z, sc);
            float Id = fabsf(bv) * __fdividef(1.0f, z * z);
            sVdf = fmaf(wyd, Id, sVdf);
        }
    }
    double sVc = (double)sVcf, sVd = (double)sVdf;
    block_reduce2(sVc, sVd, red, tid);
    double elc = exp((double)logcoef[0]);
    double Vc = elc * PI_D * 4.0 * sVc / zs;
    double Vd = elc * PI_D * 2.0 * (1.0 - zs) * (0.5 * Y0C + sVd);
    double outv = Vc - Vd;

    if (tid == 0) {
        if (out_size >= 2 * B) {   // complex64 layout: interleaved re, im
            out[2 * blk]     = (float)outv;
            out[2 * blk + 1] = 0.0f;
        } else {
            out[blk] = (float)outv;
        }
    }
}

extern "C" void kernel_launch(void* const* d_in, const int* in_sizes, int n_in,
                              void* d_out, int out_size, void* d_ws, size_t ws_size,
                              hipStream_t stream) {
    const float* Ls = (const float*)d_in[0];
    const float* a  = (const float*)d_in[1];
    const float* b  = (const float*)d_in[2];
    const float* lc = (const float*)d_in[3];
    float* W = (float*)d_ws;
    int B = in_sizes[0];

    hipLaunchKernelGGL(k_grid, dim3(NGRID), dim3(512), 0, stream, a, b, W);
    hipLaunchKernelGGL(k_newton, dim3(B), dim3(512), 0, stream,
                       Ls, a, b, lc, W, (float*)d_out, out_size, B);
}

// Round 16
// 18.082 us; speedup vs baseline: 4.3281x; 1.1507x over previous
//
#include <hip/hip_runtime.h>
#include <math.h>

#define NPTS 1000
#define NGRID 256
#define NEWTON_ITERS 1
#define PI_D 3.14159265358979323846

// Y grid: linspace(1e-3, 0.999, 1000). YD grid: linspace(1e-3, 1.0, 1000).
#define HY   ((0.999 - 1e-3) / 999.0)
#define Y0C  (1e-3)
#define HD   ((1.0 - 1e-3) / 999.0)

// trapz+extrapolation weights (closed form — uniform grid)
#define WY0   (0.5 * HY + Y0C + 0.5 * Y0C * Y0C / HY)
#define WY1   (HY - 0.5 * Y0C * Y0C / HY)
#define WY999 (0.5 * HY + 0.5 * (1.0 - 0.999))
#define WD0   (0.5 * (Y0C + HD))
#define WD999 (0.5 * HD)

struct SCf {
    float c[11], pc[11], bc[6], dbc[5], S, sa;
};

// Per-thread f32 coefficient folding (~70 FLOPs, all-register).
__device__ inline void make_scf(const float* a, const float* b, SCf& s) {
    float af[6], bf[6];
    af[0] = 1.0f; bf[0] = 1.0f;
    #pragma unroll
    for (int i = 0; i < 5; ++i) { af[i+1] = a[i]; bf[i+1] = b[i]; }
    #pragma unroll
    for (int k = 0; k < 11; ++k) s.c[k] = 0.0f;
    #pragma unroll
    for (int i = 0; i < 6; ++i)
        #pragma unroll
        for (int j = 0; j < 6; ++j)
            s.c[i+j] = fmaf(4.0f * af[i], af[j], s.c[i+j]);
    const float INVK[11] = { -0.25f, -1.0f/3.0f, -0.5f, -1.0f, 0.0f,
                              1.0f, 0.5f, 1.0f/3.0f, 0.25f, 0.2f, 1.0f/6.0f };
    float S = 0.0f;
    #pragma unroll
    for (int k = 0; k < 11; ++k) { s.pc[k] = s.c[k] * INVK[k]; S += s.pc[k]; }
    s.S = S;
    float sa = 0.0f;
    #pragma unroll
    for (int i = 0; i < 5; ++i) sa = fmaf(a[i], a[i], sa);
    s.sa = sa;
    #pragma unroll
    for (int i = 0; i < 6; ++i) s.bc[i] = bf[i];
    #pragma unroll
    for (int i = 1; i < 6; ++i) s.dbc[i-1] = (float)i * bf[i];
}

__device__ inline float eval_f_f(float z, float lnz, float z4, const SCf& s) {
    float P = s.pc[10];
    #pragma unroll
    for (int k = 9; k >= 0; --k) P = fmaf(P, z, s.pc[k]);
    return s.S * z4 - P - s.c[4] * z4 * lnz + 0.004f * s.sa * z4 * (1.0f - z);
}
__device__ inline float eval_Q_f(float z, const SCf& s) {
    float Q = s.c[10];
    #pragma unroll
    for (int k = 9; k >= 0; --k) Q = fmaf(Q, z, s.c[k]);
    return Q;
}
__device__ inline float eval_bv_f(float z, const SCf& s) {
    float B = s.bc[5];
    #pragma unroll
    for (int k = 4; k >= 0; --k) B = fmaf(B, z, s.bc[k]);
    return B;
}
__device__ inline float eval_dbv_f(float z, const SCf& s) {
    float D = s.dbc[4];
    #pragma unroll
    for (int k = 3; k >= 0; --k) D = fmaf(D, z, s.dbc[k]);
    return D;
}

struct PtCf { float y, u, lnu, wt, inv_u; };
struct ItSf { float zs, lnzs, zs4, fs, inv_fs, inv_zs, sdf; };

// Per-thread point constants (f32 hot ops; y from f64 fma for grid fidelity).
__device__ inline void make_points(int tid, PtCf* p) {
    #pragma unroll
    for (int j = 0; j < 2; ++j) {
        int k = tid + j * 512;
        int kk = (k < NPTS) ? k : (NPTS - 1);
        float y = (float)(Y0C + (double)kk * HY);
        float u = (1.0f - y) * (1.0f + y);
        p[j].y = y;
        p[j].u = u;
        p[j].lnu = __logf(u);
        p[j].inv_u = __fdividef(1.0f, u);
        float wt;
        if (k >= NPTS)      wt = 0.0f;
        else if (k == 0)    wt = (float)WY0;
        else if (k == 1)    wt = (float)WY1;
        else if (k == 999)  wt = (float)WY999;
        else                wt = (float)HY;
        p[j].wt = wt;
    }
}

__device__ inline void iter_scalars_f(float zs, const SCf& s, ItSf& it) {
    it.zs = zs;
    it.lnzs = __logf(zs);
    float z2 = zs * zs;
    it.zs4 = z2 * z2;
    it.inv_zs = __fdividef(1.0f, zs);
    float f = eval_f_f(zs, it.lnzs, it.zs4, s);
    float Q = eval_Q_f(zs, s);
    float dfs = (4.0f * f - Q) * it.inv_zs - 0.004f * s.sa * it.zs4;
    it.fs = f;
    it.inv_fs = __fdividef(1.0f, f);
    it.sdf = zs * dfs * it.inv_fs;   // zs*dfs/fs
}

// Combined L / dL integrands (f32). sqrt(1-z/zs)=y; 1/(Am1^1.5)=rsqrt^3.
template <bool NL, bool ND>
__device__ inline void integrands_f(const PtCf& p, const ItSf& is, const SCf& s,
                                    float& IL, float& ID) {
    float u = p.u;
    float w2 = u * u, w4 = w2 * w2;
    float z   = is.zs * u;
    float lnz = is.lnzs + p.lnu;
    float z4  = is.zs4 * w4;
    float f = eval_f_f(z, lnz, z4, s);
    float bv = eval_bv_f(z, s);
    float inv_f = __fdividef(1.0f, f);
    float sqrtg = fabsf(bv) * rsqrtf(f);
    float fofs = f * is.inv_fs;
    float iu2 = p.inv_u * p.inv_u;
    float r4 = iu2 * iu2;                // zs^4/z^4
    float A = fofs * r4;
    float r = rsqrtf(A - 1.0f);
    if (NL) {
        IL = sqrtg * p.y * r;
    }
    if (ND) {
        float Q = eval_Q_f(z, s);
        float inv_z = is.inv_zs * p.inv_u;
        float df = (4.0f * f - Q) * inv_z - 0.004f * s.sa * z4;
        float dbv = eval_dbv_f(z, s);
        float t = z * (2.0f * __fdividef(dbv, bv) - df * inv_f);   // z*dg/g
        float i1 = A * (is.sdf + 2.0f + t) - r4 * z * df * is.inv_fs - 2.0f - t;
        ID = i1 * 2.0f * p.y * sqrtg * (r * r * r);
    }
}

// deterministic block reduction of 2 floats (512 threads = 8 waves)
__device__ inline void block_reduce2f(float& sx, float& sy, float2* lds, int tid) {
    #pragma unroll
    for (int off = 32; off > 0; off >>= 1) {
        sx += __shfl_xor(sx, off);
        sy += __shfl_xor(sy, off);
    }
    int wid = tid >> 6;
    if ((tid & 63) == 0) lds[wid] = make_float2(sx, sy);
    __syncthreads();
    float rx = 0.0f, ry = 0.0f;
    #pragma unroll
    for (int w = 0; w < 8; ++w) { rx += lds[w].x; ry += lds[w].y; }
    __syncthreads();
    sx = rx; sy = ry;
}

__device__ inline double grid_zs(int i) {
    return 0.05 + (double)i * (0.999 - 0.05) / 255.0;
}

// ---- Kernel 1: Lg (masked to rising branch) over a FIXED zs grid ----
__global__ __launch_bounds__(512, 4) void k_grid(const float* a, const float* b, float* W) {
    __shared__ float2 red[8];
    int tid = threadIdx.x, blk = blockIdx.x;
    SCf sc;
    make_scf(a, b, sc);
    PtCf p[2];
    make_points(tid, p);

    float zs = (float)grid_zs(blk);
    ItSf is;
    iter_scalars_f(zs, sc, is);
    float sLf = 0.0f, sDf = 0.0f;
    #pragma unroll
    for (int j = 0; j < 2; ++j) {
        float IL, ID;
        integrands_f<true, true>(p[j], is, sc, IL, ID);
        sLf = fmaf(p[j].wt, IL, sLf);
        sDf = fmaf(p[j].wt, ID, sDf);
    }
    block_reduce2f(sLf, sDf, red, tid);
    if (tid == 0) {
        // mask non-rising-branch candidates (dL <= 0)
        W[blk] = (sDf > 0.0f) ? (float)(4.0 * (double)zs * (double)sLf / PI_D) : 1e30f;
    }
}

// ---- Kernel 2: interp init + 1 Newton + Vc/Vd ----
__global__ __launch_bounds__(512, 4) void k_newton(const float* Ls, const float* a,
                                                   const float* b, const float* logcoef,
                                                   const float* W, float* out,
                                                   int out_size, int B) {
    __shared__ float2 red[8];
    __shared__ float wv[8];
    __shared__ int wi[8];
    int tid = threadIdx.x, blk = blockIdx.x;
    SCf sc;
    make_scf(a, b, sc);

    float Ltf = Ls[blk];
    double Lt = (double)Ltf;

    // argmin |Lg - L| over 256 masked entries (first-min tie-break)
    float v = (tid < NGRID) ? fabsf(W[tid] - Ltf) : 3e38f;
    int idx = (tid < NGRID) ? tid : (1 << 30);
    #pragma unroll
    for (int off = 32; off > 0; off >>= 1) {
        float ov = __shfl_xor(v, off);
        int oi = __shfl_xor(idx, off);
        if (ov < v || (ov == v && oi < idx)) { v = ov; idx = oi; }
    }
    if ((tid & 63) == 0) { wv[tid >> 6] = v; wi[tid >> 6] = idx; }
    __syncthreads();
    v = wv[0]; idx = wi[0];
    #pragma unroll
    for (int w = 1; w < 8; ++w) {
        if (wv[w] < v || (wv[w] == v && wi[w] < idx)) { v = wv[w]; idx = wi[w]; }
    }

    // Linear-interp init within the bracketing cell (better e0 -> 1 Newton iter).
    double zs = grid_zs(idx);
    {
        float Lg0 = W[idx];
        if (Lg0 < 1e29f) {
            int nb = (Lg0 <= Ltf) ? idx + 1 : idx - 1;
            if (nb >= 0 && nb < NGRID) {
                float Lg1 = W[nb];
                if (Lg1 < 1e29f && Lg1 != Lg0) {
                    float tf = __fdividef(Ltf - Lg0, Lg1 - Lg0);
                    tf = fminf(fmaxf(tf, 0.0f), 1.0f);
                    zs = zs + (double)tf * (grid_zs(nb) - grid_zs(idx));
                }
            }
        }
    }

    PtCf p[2];
    make_points(tid, p);

    // Newton (combined L + dL pass; f32 integrands, f64 scalar update)
    for (int itn = 0; itn < NEWTON_ITERS; ++itn) {
        ItSf is;
        iter_scalars_f((float)zs, sc, is);
        float sLf = 0.0f, sDf = 0.0f;
        #pragma unroll
        for (int j = 0; j < 2; ++j) {
            float IL, ID;
            integrands_f<true, true>(p[j], is, sc, IL, ID);
            sLf = fmaf(p[j].wt, IL, sLf);
            sDf = fmaf(p[j].wt, ID, sDf);
        }
        block_reduce2f(sLf, sDf, red, tid);
        double L_  = 4.0 * zs * (double)sLf / PI_D;
        double dL  = (double)sDf / PI_D;
        zs = zs - (L_ - Lt) / dL;
        zs = fmin(fmax(zs, 1e-3), 0.999);   // domain clamp (no-op at convergence)
    }

    // Vc (Y grid) + Vd (YD grid), fused; sqrt(f*g)=|bv| exactly.
    ItSf is;
    iter_scalars_f((float)zs, sc, is);
    float omzs = (float)(1.0 - zs);
    float sVcf = 0.0f, sVdf = 0.0f;
    #pragma unroll
    for (int j = 0; j < 2; ++j) {
        int k = tid + j * 512;
        int kk = (k < NPTS) ? k : (NPTS - 1);
        {   // connected: z = zs*(1-y)(1+y)
            float u = p[j].u;
            float w2 = u * u, w4 = w2 * w2;
            float z   = is.zs * u;
            float lnz = is.lnzs + p[j].lnu;
            float z4  = is.zs4 * w4;
            float f = eval_f_f(z, lnz, z4, sc);
            float bv = eval_bv_f(z, sc);
            float inv_f = __fdividef(1.0f, f);
            float iu2 = p[j].inv_u * p[j].inv_u;
            float arg = fmaf(-w4 * is.fs, inv_f, 1.0f);   // 1 - w4*fs/f
            float Ic = fabsf(bv) * (rsqrtf(arg) - 1.0f) * p[j].y * iu2;
            sVcf = fmaf(p[j].wt, Ic, sVcf);
        }
        {   // disconnected: z = 1-(1-zs)*yd ; integrand = |bv(z)|/z^2
            float yd = (float)(Y0C + (double)kk * HD);
            float wyd;
            if (k >= NPTS)      wyd = 0.0f;
            else if (k == 0)    wyd = (float)WD0;
            else if (k == 999)  wyd = (float)WD999;
            else                wyd = (float)HD;
            float z = fmaf(-omzs, yd, 1.0f);
            float bv = eval_bv_f(z, sc);
            float Id = fabsf(bv) * __fdividef(1.0f, z * z);
            sVdf = fmaf(wyd, Id, sVdf);
        }
    }
    block_reduce2f(sVcf, sVdf, red, tid);
    double elc = exp((double)logcoef[0]);
    double Vc = elc * PI_D * 4.0 * (double)sVcf / zs;
    double Vd = elc * PI_D * 2.0 * (1.0 - zs) * (0.5 * Y0C + (double)sVdf);
    double outv = Vc - Vd;

    if (tid == 0) {
        if (out_size >= 2 * B) {   // complex64 layout: interleaved re, im
            out[2 * blk]     = (float)outv;
            out[2 * blk + 1] = 0.0f;
        } else {
            out[blk] = (float)outv;
        }
    }
}

extern "C" void kernel_launch(void* const* d_in, const int* in_sizes, int n_in,
                              void* d_out, int out_size, void* d_ws, size_t ws_size,
                              hipStream_t stream) {
    const float* Ls = (const float*)d_in[0];
    const float* a  = (const float*)d_in[1];
    const float* b  = (const float*)d_in[2];
    const float* lc = (const float*)d_in[3];
    float* W = (float*)d_ws;
    int B = in_sizes[0];

    hipLaunchKernelGGL(k_grid, dim3(NGRID), dim3(512), 0, stream, a, b, W);
    hipLaunchKernelGGL(k_newton, dim3(B), dim3(512), 0, stream,
                       Ls, a, b, lc, W, (float*)d_out, out_size, B);
}